// Round 11
// baseline (348.679 us; speedup 1.0000x reference)
//
#include <hip/hip_runtime.h>
#include <hip/hip_bf16.h>

#define T_TOK 2048
#define DDIM  1024
#define IDIM  1024
#define NEXP  8
#define TOPK  2
#define MAXROWS (T_TOK * TOPK)

#define BM 128          // block rows (4 waves x 32)
#define WN 32           // wave cols
#define BK 32

typedef __attribute__((ext_vector_type(8))) short          s16x8;
typedef __attribute__((ext_vector_type(8))) unsigned short u16x8;
typedef __attribute__((ext_vector_type(4))) float          f32x4;

__device__ __forceinline__ unsigned short f2bf(float f) {
    return __builtin_bit_cast(unsigned short, __float2bfloat16(f));
}

__device__ __forceinline__ u16x8 pack8(const float4& a, const float4& b) {
    u16x8 v;
    v[0] = f2bf(a.x); v[1] = f2bf(a.y); v[2] = f2bf(a.z); v[3] = f2bf(a.w);
    v[4] = f2bf(b.x); v[5] = f2bf(b.y); v[6] = f2bf(b.z); v[7] = f2bf(b.w);
    return v;
}

__device__ __forceinline__ s16x8 cvt8(const float4& a, const float4& b) {
    return __builtin_bit_cast(s16x8, pack8(a, b));
}

// ---------------- routing: build per-expert compact token lists ----------------
__global__ void route_kernel(const int* __restrict__ indices,
                             const float* __restrict__ weights,
                             const void* __restrict__ mask,
                             int* __restrict__ counts, int* __restrict__ offsets,
                             int* __restrict__ tok, float* __restrict__ wslot) {
    __shared__ int cnt[NEXP], offs[NEXP], cur[NEXP];
    __shared__ int is_u8;
    const int tid = threadIdx.x;
    const unsigned char* m8  = (const unsigned char*)mask;
    const int*           m32 = (const int*)mask;
    if (tid < NEXP) cnt[tid] = 0;
    if (tid == 0) is_u8 = 0;
    __syncthreads();
    int found = 0;
    for (int i = tid; i < T_TOK; i += blockDim.x)
        if ((i & 3) != 0 && m8[i] != 0) found = 1;
    if (found) atomicOr(&is_u8, 1);
    __syncthreads();
    const int u8mode = is_u8;
    for (int idx = tid; idx < MAXROWS; idx += blockDim.x) {
        int t = idx >> 1;  // K = 2
        int active = u8mode ? (m8[t] != 0) : (m32[t] != 0);
        if (active) atomicAdd(&cnt[indices[idx]], 1);
    }
    __syncthreads();
    if (tid == 0) {
        int run = 0;
        for (int e = 0; e < NEXP; ++e) { offs[e] = run; run += cnt[e]; }
    }
    __syncthreads();
    if (tid < NEXP) { counts[tid] = cnt[tid]; offsets[tid] = offs[tid]; cur[tid] = offs[tid]; }
    __syncthreads();
    for (int idx = tid; idx < MAXROWS; idx += blockDim.x) {
        int t = idx >> 1;
        int active = u8mode ? (m8[t] != 0) : (m32[t] != 0);
        if (active) {
            int e = indices[idx];
            int p = atomicAdd(&cur[e], 1);
            tok[p]   = t;
            wslot[p] = weights[idx];
        }
    }
}

// ---------------- x: f32 -> bf16 once ----------------
__global__ __launch_bounds__(256) void cvt_x_kernel(const float* __restrict__ x,
                                                    unsigned short* __restrict__ xb) {
    int i = (blockIdx.x * 256 + threadIdx.x) * 8;
    float4 a = *reinterpret_cast<const float4*>(x + i);
    float4 b = *reinterpret_cast<const float4*>(x + i + 4);
    *reinterpret_cast<u16x8*>(xb + i) = pack8(a, b);
}

// ---------------- GEMM1: register-direct flatmm, no LDS / no barriers ----------------
// 4 waves; wave w owns rows [tileM*128 + w*32, +32) x cols [n0, n0+32).
__global__ __launch_bounds__(256) void gemm1_kernel(
    const unsigned short* __restrict__ xb,
    const float* __restrict__ gate, const float* __restrict__ up,
    const int* __restrict__ counts, const int* __restrict__ offsets,
    const int* __restrict__ tok, unsigned short* __restrict__ hb) {
    const int e     = blockIdx.z;
    const int n_e   = counts[e];
    const int tileM = blockIdx.y;
    if (tileM * BM >= n_e) return;
    const int off = offsets[e];
    const int n0  = blockIdx.x * WN;

    const int tid  = threadIdx.x;
    const int lane = tid & 63;
    const int wid  = tid >> 6;
    const int fr   = lane & 15;
    const int s8   = lane >> 4;

    const int rbase = tileM * BM + wid * 32;
    int r0 = rbase + fr, r1 = rbase + 16 + fr;
    int t0 = (r0 < n_e) ? tok[off + r0] : tok[off];
    int t1 = (r1 < n_e) ? tok[off + r1] : tok[off];
    const unsigned short* aP0 = xb + (size_t)t0 * DDIM + s8 * 8;
    const unsigned short* aP1 = xb + (size_t)t1 * DDIM + s8 * 8;
    const float* gP0 = gate + ((size_t)e * IDIM + n0 + fr) * DDIM + s8 * 8;
    const float* gP1 = gate + ((size_t)e * IDIM + n0 + 16 + fr) * DDIM + s8 * 8;
    const float* uP0 = up   + ((size_t)e * IDIM + n0 + fr) * DDIM + s8 * 8;
    const float* uP1 = up   + ((size_t)e * IDIM + n0 + 16 + fr) * DDIM + s8 * 8;

    f32x4 accg[2][2] = {};
    f32x4 accu[2][2] = {};

#pragma unroll 2
    for (int k0 = 0; k0 < DDIM; k0 += BK) {
        s16x8 a0 = *reinterpret_cast<const s16x8*>(aP0 + k0);
        s16x8 a1 = *reinterpret_cast<const s16x8*>(aP1 + k0);
        float4 g00 = *reinterpret_cast<const float4*>(gP0 + k0);
        float4 g01 = *reinterpret_cast<const float4*>(gP0 + k0 + 4);
        float4 g10 = *reinterpret_cast<const float4*>(gP1 + k0);
        float4 g11 = *reinterpret_cast<const float4*>(gP1 + k0 + 4);
        float4 u00 = *reinterpret_cast<const float4*>(uP0 + k0);
        float4 u01 = *reinterpret_cast<const float4*>(uP0 + k0 + 4);
        float4 u10 = *reinterpret_cast<const float4*>(uP1 + k0);
        float4 u11 = *reinterpret_cast<const float4*>(uP1 + k0 + 4);
        s16x8 bg0 = cvt8(g00, g01);
        s16x8 bg1 = cvt8(g10, g11);
        s16x8 bu0 = cvt8(u00, u01);
        s16x8 bu1 = cvt8(u10, u11);
        accg[0][0] = __builtin_amdgcn_mfma_f32_16x16x32_bf16(a0, bg0, accg[0][0], 0, 0, 0);
        accg[0][1] = __builtin_amdgcn_mfma_f32_16x16x32_bf16(a0, bg1, accg[0][1], 0, 0, 0);
        accg[1][0] = __builtin_amdgcn_mfma_f32_16x16x32_bf16(a1, bg0, accg[1][0], 0, 0, 0);
        accg[1][1] = __builtin_amdgcn_mfma_f32_16x16x32_bf16(a1, bg1, accg[1][1], 0, 0, 0);
        accu[0][0] = __builtin_amdgcn_mfma_f32_16x16x32_bf16(a0, bu0, accu[0][0], 0, 0, 0);
        accu[0][1] = __builtin_amdgcn_mfma_f32_16x16x32_bf16(a0, bu1, accu[0][1], 0, 0, 0);
        accu[1][0] = __builtin_amdgcn_mfma_f32_16x16x32_bf16(a1, bu0, accu[1][0], 0, 0, 0);
        accu[1][1] = __builtin_amdgcn_mfma_f32_16x16x32_bf16(a1, bu1, accu[1][1], 0, 0, 0);
    }

#pragma unroll
    for (int m = 0; m < 2; ++m)
#pragma unroll
        for (int n = 0; n < 2; ++n)
#pragma unroll
            for (int j = 0; j < 4; ++j) {
                int rl = rbase + m * 16 + s8 * 4 + j;
                if (rl < n_e) {
                    int col = n0 + n * 16 + fr;
                    float g = accg[m][n][j];
                    float u = accu[m][n][j];
                    float h = (g / (1.0f + __expf(-g))) * u;
                    hb[(size_t)(off + rl) * IDIM + col] = f2bf(h);
                }
            }
}

// ---------------- GEMM2: register-direct flatmm, weighted scatter-add ----------------
__global__ __launch_bounds__(256) void gemm2_kernel(
    const unsigned short* __restrict__ hb, const float* __restrict__ down,
    const int* __restrict__ counts, const int* __restrict__ offsets,
    const int* __restrict__ tok, const float* __restrict__ wslot,
    float* __restrict__ y) {
    const int e     = blockIdx.z;
    const int n_e   = counts[e];
    const int tileM = blockIdx.y;
    if (tileM * BM >= n_e) return;
    const int off = offsets[e];
    const int n0  = blockIdx.x * WN;

    const int tid  = threadIdx.x;
    const int lane = tid & 63;
    const int wid  = tid >> 6;
    const int fr   = lane & 15;
    const int s8   = lane >> 4;

    const int rbase = tileM * BM + wid * 32;
    int r0 = rbase + fr, r1 = rbase + 16 + fr;
    int h0 = (r0 < n_e) ? (off + r0) : off;
    int h1 = (r1 < n_e) ? (off + r1) : off;
    const unsigned short* aP0 = hb + (size_t)h0 * IDIM + s8 * 8;
    const unsigned short* aP1 = hb + (size_t)h1 * IDIM + s8 * 8;
    const float* bP0 = down + ((size_t)e * DDIM + n0 + fr) * IDIM + s8 * 8;
    const float* bP1 = down + ((size_t)e * DDIM + n0 + 16 + fr) * IDIM + s8 * 8;

    f32x4 acc[2][2] = {};

#pragma unroll 2
    for (int k0 = 0; k0 < IDIM; k0 += BK) {
        s16x8 a0 = *reinterpret_cast<const s16x8*>(aP0 + k0);
        s16x8 a1 = *reinterpret_cast<const s16x8*>(aP1 + k0);
        float4 b00 = *reinterpret_cast<const float4*>(bP0 + k0);
        float4 b01 = *reinterpret_cast<const float4*>(bP0 + k0 + 4);
        float4 b10 = *reinterpret_cast<const float4*>(bP1 + k0);
        float4 b11 = *reinterpret_cast<const float4*>(bP1 + k0 + 4);
        s16x8 bf0 = cvt8(b00, b01);
        s16x8 bf1 = cvt8(b10, b11);
        acc[0][0] = __builtin_amdgcn_mfma_f32_16x16x32_bf16(a0, bf0, acc[0][0], 0, 0, 0);
        acc[0][1] = __builtin_amdgcn_mfma_f32_16x16x32_bf16(a0, bf1, acc[0][1], 0, 0, 0);
        acc[1][0] = __builtin_amdgcn_mfma_f32_16x16x32_bf16(a1, bf0, acc[1][0], 0, 0, 0);
        acc[1][1] = __builtin_amdgcn_mfma_f32_16x16x32_bf16(a1, bf1, acc[1][1], 0, 0, 0);
    }

#pragma unroll
    for (int m = 0; m < 2; ++m)
#pragma unroll
        for (int n = 0; n < 2; ++n)
#pragma unroll
            for (int j = 0; j < 4; ++j) {
                int rl = rbase + m * 16 + s8 * 4 + j;
                if (rl < n_e) {
                    int col = n0 + n * 16 + fr;
                    int row = off + rl;
                    float v = acc[m][n][j] * wslot[row];
                    atomicAdd(&y[(size_t)tok[row] * DDIM + col], v);
                }
            }
}

extern "C" void kernel_launch(void* const* d_in, const int* in_sizes, int n_in,
                              void* d_out, int out_size, void* d_ws, size_t ws_size,
                              hipStream_t stream) {
    const float* x       = (const float*)d_in[0];
    const void*  mask    = d_in[1];
    const float* weights = (const float*)d_in[2];
    const int*   indices = (const int*)d_in[3];
    const float* gate    = (const float*)d_in[4];
    const float* up      = (const float*)d_in[5];
    const float* down    = (const float*)d_in[6];
    float*       y       = (float*)d_out;

    char* ws = (char*)d_ws;
    int*            counts  = (int*)ws;
    int*            offsets = (int*)(ws + 32);
    int*            tok     = (int*)(ws + 256);
    float*          wslot   = (float*)(ws + 256 + MAXROWS * 4);
    unsigned short* xb      = (unsigned short*)(ws + 65536);
    unsigned short* hb      = (unsigned short*)(ws + 65536 + (size_t)T_TOK * DDIM * 2);

    hipMemsetAsync(d_out, 0, (size_t)out_size * sizeof(float), stream);
    route_kernel<<<1, 256, 0, stream>>>(indices, weights, mask, counts, offsets, tok, wslot);
    cvt_x_kernel<<<(T_TOK * DDIM / 8) / 256, 256, 0, stream>>>(x, xb);

    dim3 g1(IDIM / WN, MAXROWS / BM, NEXP);   // 32 x 32 x 8 (most m-tiles early-return)
    gemm1_kernel<<<g1, 256, 0, stream>>>(xb, gate, up, counts, offsets, tok, hb);
    dim3 g2(DDIM / WN, MAXROWS / BM, NEXP);
    gemm2_kernel<<<g2, 256, 0, stream>>>(hb, down, counts, offsets, tok, wslot, y);
}

// Round 12
// 164.151 us; speedup vs baseline: 2.1241x; 2.1241x over previous
//
#include <hip/hip_runtime.h>
#include <hip/hip_bf16.h>

#define T_TOK 2048
#define DDIM  1024
#define IDIM  1024
#define NEXP  8
#define TOPK  2
#define MAXROWS (T_TOK * TOPK)

#define BM 64
#define BN 64
#define BK 32

typedef __attribute__((ext_vector_type(8))) short          s16x8;
typedef __attribute__((ext_vector_type(8))) unsigned short u16x8;
typedef __attribute__((ext_vector_type(4))) float          f32x4;

__device__ __forceinline__ unsigned short f2bf(float f) {
    return __builtin_bit_cast(unsigned short, __float2bfloat16(f));
}

__device__ __forceinline__ u16x8 pack8(const float4& a, const float4& b) {
    u16x8 v;
    v[0] = f2bf(a.x); v[1] = f2bf(a.y); v[2] = f2bf(a.z); v[3] = f2bf(a.w);
    v[4] = f2bf(b.x); v[5] = f2bf(b.y); v[6] = f2bf(b.z); v[7] = f2bf(b.w);
    return v;
}

__device__ __forceinline__ s16x8 cvt8(const float4& a, const float4& b) {
    return __builtin_bit_cast(s16x8, pack8(a, b));
}

// async global -> LDS, 16 B per lane. Global address is PER-LANE; LDS dest is
// wave-uniform base + lane*16 (linear).
__device__ __forceinline__ void gll16(const void* g, void* l) {
    __builtin_amdgcn_global_load_lds(
        (const __attribute__((address_space(1))) void*)g,
        (__attribute__((address_space(3))) void*)l, 16, 0, 0);
}

// ---------------- routing: build per-expert compact token lists ----------------
__global__ void route_kernel(const int* __restrict__ indices,
                             const float* __restrict__ weights,
                             const void* __restrict__ mask,
                             int* __restrict__ counts, int* __restrict__ offsets,
                             int* __restrict__ tok, float* __restrict__ wslot) {
    __shared__ int cnt[NEXP], offs[NEXP], cur[NEXP];
    __shared__ int is_u8;
    const int tid = threadIdx.x;
    const unsigned char* m8  = (const unsigned char*)mask;
    const int*           m32 = (const int*)mask;
    if (tid < NEXP) cnt[tid] = 0;
    if (tid == 0) is_u8 = 0;
    __syncthreads();
    int found = 0;
    for (int i = tid; i < T_TOK; i += blockDim.x)
        if ((i & 3) != 0 && m8[i] != 0) found = 1;
    if (found) atomicOr(&is_u8, 1);
    __syncthreads();
    const int u8mode = is_u8;
    for (int idx = tid; idx < MAXROWS; idx += blockDim.x) {
        int t = idx >> 1;  // K = 2
        int active = u8mode ? (m8[t] != 0) : (m32[t] != 0);
        if (active) atomicAdd(&cnt[indices[idx]], 1);
    }
    __syncthreads();
    if (tid == 0) {
        int run = 0;
        for (int e = 0; e < NEXP; ++e) { offs[e] = run; run += cnt[e]; }
    }
    __syncthreads();
    if (tid < NEXP) { counts[tid] = cnt[tid]; offsets[tid] = offs[tid]; cur[tid] = offs[tid]; }
    __syncthreads();
    for (int idx = tid; idx < MAXROWS; idx += blockDim.x) {
        int t = idx >> 1;
        int active = u8mode ? (m8[t] != 0) : (m32[t] != 0);
        if (active) {
            int e = indices[idx];
            int p = atomicAdd(&cur[e], 1);
            tok[p]   = t;
            wslot[p] = weights[idx];
        }
    }
}

// ---------------- x: f32 -> bf16 once ----------------
__global__ __launch_bounds__(256) void cvt_x_kernel(const float* __restrict__ x,
                                                    unsigned short* __restrict__ xb) {
    int i = (blockIdx.x * 256 + threadIdx.x) * 8;
    float4 a = *reinterpret_cast<const float4*>(x + i);
    float4 b = *reinterpret_cast<const float4*>(x + i + 4);
    *reinterpret_cast<u16x8*>(xb + i) = pack8(a, b);
}

// LDS layouts (128-B rows, XOR-swizzled slot ^= row&7, rule #21) — identical to R6/R7.

// ---------------- GEMM1: gll + 3-stage counted-vmcnt pipeline ----------------
__global__ __launch_bounds__(256) void gemm1_kernel(
    const unsigned short* __restrict__ xb,
    const float* __restrict__ gate, const float* __restrict__ up,
    const int* __restrict__ counts, const int* __restrict__ offsets,
    const int* __restrict__ tok, unsigned short* __restrict__ hb) {
    const int e     = blockIdx.z;
    const int n_e   = counts[e];
    const int tileM = blockIdx.y;
    if (tileM * BM >= n_e) return;
    const int off = offsets[e];
    const int n0  = blockIdx.x * BN;

    __shared__ unsigned short lA[3][2048];  // 3 x 4 KB
    __shared__ float          lG[3][2048];  // 3 x 8 KB
    __shared__ float          lU[3][2048];  // 3 x 8 KB  -> 60 KB

    const int tid  = threadIdx.x;
    const int lane = tid & 63;
    const int wid  = tid >> 6;
    const int wm   = wid >> 1, wn = wid & 1;

    const int rA  = wid * 8 + (lane >> 3);
    const int ilA = (lane & 7) ^ (rA & 7);
    const int trA = 2 * rA + (ilA & 1);
    const int rowIdxA = tileM * BM + trA;
    const int tIdxA = (rowIdxA < n_e) ? tok[off + rowIdxA] : tok[off];
    const unsigned short* aSrc = xb + (size_t)tIdxA * DDIM + (ilA >> 1) * 8;
    const int rB0 = (2 * wid) * 8 + (lane >> 3);
    const int rB1 = rB0 + 8;
    const int ilB0 = (lane & 7) ^ (rB0 & 7);
    const int ilB1 = (lane & 7) ^ (rB1 & 7);
    const float* gSrc0 = gate + ((size_t)e * IDIM + n0 + rB0) * DDIM + ilB0 * 4;
    const float* gSrc1 = gate + ((size_t)e * IDIM + n0 + rB1) * DDIM + ilB1 * 4;
    const float* uSrc0 = up   + ((size_t)e * IDIM + n0 + rB0) * DDIM + ilB0 * 4;
    const float* uSrc1 = up   + ((size_t)e * IDIM + n0 + rB1) * DDIM + ilB1 * 4;

    f32x4 accg[2][2] = {};
    f32x4 accu[2][2] = {};

    const int fr = lane & 15;
    const int s8 = lane >> 4;

    auto STAGE = [&](int b, int t) {
        const int k0 = t * BK;
        gll16(aSrc  + k0, &lA[b][wid * 512]);
        gll16(gSrc0 + k0, &lG[b][(2 * wid) * 256]);
        gll16(gSrc1 + k0, &lG[b][(2 * wid + 1) * 256]);
        gll16(uSrc0 + k0, &lU[b][(2 * wid) * 256]);
        gll16(uSrc1 + k0, &lU[b][(2 * wid + 1) * 256]);
    };

    auto COMPUTE = [&](int b) {
        s16x8 a[2];
#pragma unroll
        for (int m = 0; m < 2; ++m) {
            int trow = wm * 32 + m * 16 + fr;
            int r = trow >> 1, p = trow & 1;
            int is_ = (2 * s8 + p) ^ (r & 7);
            a[m] = *reinterpret_cast<const s16x8*>(&lA[b][r * 64 + is_ * 8]);
        }
        s16x8 bg[2], bu[2];
#pragma unroll
        for (int nf = 0; nf < 2; ++nf) {
            int n = wn * 32 + nf * 16 + fr;
            int xr = n & 7;
            float4 g0 = *reinterpret_cast<const float4*>(&lG[b][n * 32 + ((2 * s8) ^ xr) * 4]);
            float4 g1 = *reinterpret_cast<const float4*>(&lG[b][n * 32 + ((2 * s8 + 1) ^ xr) * 4]);
            float4 u0 = *reinterpret_cast<const float4*>(&lU[b][n * 32 + ((2 * s8) ^ xr) * 4]);
            float4 u1 = *reinterpret_cast<const float4*>(&lU[b][n * 32 + ((2 * s8 + 1) ^ xr) * 4]);
            bg[nf] = cvt8(g0, g1);
            bu[nf] = cvt8(u0, u1);
        }
#pragma unroll
        for (int m = 0; m < 2; ++m)
#pragma unroll
            for (int nf = 0; nf < 2; ++nf) {
                accg[m][nf] = __builtin_amdgcn_mfma_f32_16x16x32_bf16(a[m], bg[nf], accg[m][nf], 0, 0, 0);
                accu[m][nf] = __builtin_amdgcn_mfma_f32_16x16x32_bf16(a[m], bu[nf], accu[m][nf], 0, 0, 0);
            }
    };

    const int NT = DDIM / BK;  // 32
    STAGE(0, 0);
    STAGE(1, 1);
    for (int t = 0; t < NT; ++t) {
        if (t + 2 < NT) {
            STAGE((t + 2) % 3, t + 2);                        // 2 tiles in flight
            asm volatile("s_waitcnt vmcnt(10)" ::: "memory"); // wait tile t only (10 = t+1,t+2 loads)
        } else if (t + 1 < NT) {
            asm volatile("s_waitcnt vmcnt(5)" ::: "memory");
        } else {
            asm volatile("s_waitcnt vmcnt(0)" ::: "memory");
        }
        __builtin_amdgcn_s_barrier();                         // tile t visible to all
        __builtin_amdgcn_sched_barrier(0);
        COMPUTE(t % 3);
        asm volatile("s_waitcnt lgkmcnt(0)" ::: "memory");    // my LDS reads done
        __builtin_amdgcn_sched_barrier(0);
        __builtin_amdgcn_s_barrier();                         // buffer reusable
    }

    const int rbase = tileM * BM;
#pragma unroll
    for (int m = 0; m < 2; ++m)
#pragma unroll
        for (int n = 0; n < 2; ++n)
#pragma unroll
            for (int j = 0; j < 4; ++j) {
                int rl = wm * 32 + m * 16 + (lane >> 4) * 4 + j;
                if (rbase + rl < n_e) {
                    int col = wn * 32 + n * 16 + fr;
                    float g = accg[m][n][j];
                    float u = accu[m][n][j];
                    float h = (g / (1.0f + __expf(-g))) * u;
                    hb[(size_t)(off + rbase + rl) * IDIM + n0 + col] = f2bf(h);
                }
            }
}

// ---------------- GEMM2: gll + 3-stage counted-vmcnt pipeline, weighted scatter-add ----------------
__global__ __launch_bounds__(256) void gemm2_kernel(
    const unsigned short* __restrict__ hb, const float* __restrict__ down,
    const int* __restrict__ counts, const int* __restrict__ offsets,
    const int* __restrict__ tok, const float* __restrict__ wslot,
    float* __restrict__ y) {
    const int e     = blockIdx.z;
    const int n_e   = counts[e];
    const int tileM = blockIdx.y;
    if (tileM * BM >= n_e) return;
    const int off = offsets[e];
    const int n0  = blockIdx.x * BN;

    __shared__ unsigned short lA[3][2048];
    __shared__ float          lB[3][2048];  // 36 KB

    const int tid  = threadIdx.x;
    const int lane = tid & 63;
    const int wid  = tid >> 6;
    const int wm   = wid >> 1, wn = wid & 1;

    const int rA  = wid * 8 + (lane >> 3);
    const int ilA = (lane & 7) ^ (rA & 7);
    const int trA = 2 * rA + (ilA & 1);
    const int rowIdxA = tileM * BM + trA;
    const int hrowA = (rowIdxA < n_e) ? (off + rowIdxA) : off;
    const unsigned short* aSrc = hb + (size_t)hrowA * IDIM + (ilA >> 1) * 8;
    const int rB0 = (2 * wid) * 8 + (lane >> 3);
    const int rB1 = rB0 + 8;
    const int ilB0 = (lane & 7) ^ (rB0 & 7);
    const int ilB1 = (lane & 7) ^ (rB1 & 7);
    const float* bSrc0 = down + ((size_t)e * DDIM + n0 + rB0) * IDIM + ilB0 * 4;
    const float* bSrc1 = down + ((size_t)e * DDIM + n0 + rB1) * IDIM + ilB1 * 4;

    f32x4 acc[2][2] = {};

    const int fr = lane & 15;
    const int s8 = lane >> 4;

    auto STAGE = [&](int b, int t) {
        const int k0 = t * BK;
        gll16(aSrc  + k0, &lA[b][wid * 512]);
        gll16(bSrc0 + k0, &lB[b][(2 * wid) * 256]);
        gll16(bSrc1 + k0, &lB[b][(2 * wid + 1) * 256]);
    };

    auto COMPUTE = [&](int b) {
        s16x8 a[2];
#pragma unroll
        for (int m = 0; m < 2; ++m) {
            int trow = wm * 32 + m * 16 + fr;
            int r = trow >> 1, p = trow & 1;
            int is_ = (2 * s8 + p) ^ (r & 7);
            a[m] = *reinterpret_cast<const s16x8*>(&lA[b][r * 64 + is_ * 8]);
        }
        s16x8 bf[2];
#pragma unroll
        for (int nf = 0; nf < 2; ++nf) {
            int n = wn * 32 + nf * 16 + fr;
            int xr = n & 7;
            float4 b0 = *reinterpret_cast<const float4*>(&lB[b][n * 32 + ((2 * s8) ^ xr) * 4]);
            float4 b1 = *reinterpret_cast<const float4*>(&lB[b][n * 32 + ((2 * s8 + 1) ^ xr) * 4]);
            bf[nf] = cvt8(b0, b1);
        }
#pragma unroll
        for (int m = 0; m < 2; ++m)
#pragma unroll
            for (int nf = 0; nf < 2; ++nf)
                acc[m][nf] = __builtin_amdgcn_mfma_f32_16x16x32_bf16(a[m], bf[nf], acc[m][nf], 0, 0, 0);
    };

    const int NT = IDIM / BK;  // 32
    STAGE(0, 0);
    STAGE(1, 1);
    for (int t = 0; t < NT; ++t) {
        if (t + 2 < NT) {
            STAGE((t + 2) % 3, t + 2);
            asm volatile("s_waitcnt vmcnt(6)" ::: "memory");  // 6 = t+1,t+2 loads
        } else if (t + 1 < NT) {
            asm volatile("s_waitcnt vmcnt(3)" ::: "memory");
        } else {
            asm volatile("s_waitcnt vmcnt(0)" ::: "memory");
        }
        __builtin_amdgcn_s_barrier();
        __builtin_amdgcn_sched_barrier(0);
        COMPUTE(t % 3);
        asm volatile("s_waitcnt lgkmcnt(0)" ::: "memory");
        __builtin_amdgcn_sched_barrier(0);
        __builtin_amdgcn_s_barrier();
    }

    const int rbase = tileM * BM;
#pragma unroll
    for (int m = 0; m < 2; ++m)
#pragma unroll
        for (int n = 0; n < 2; ++n)
#pragma unroll
            for (int j = 0; j < 4; ++j) {
                int rl = wm * 32 + m * 16 + (lane >> 4) * 4 + j;
                if (rbase + rl < n_e) {
                    int col = wn * 32 + n * 16 + fr;
                    int row = off + rbase + rl;
                    float v = acc[m][n][j] * wslot[row];
                    atomicAdd(&y[(size_t)tok[row] * DDIM + n0 + col], v);
                }
            }
}

extern "C" void kernel_launch(void* const* d_in, const int* in_sizes, int n_in,
                              void* d_out, int out_size, void* d_ws, size_t ws_size,
                              hipStream_t stream) {
    const float* x       = (const float*)d_in[0];
    const void*  mask    = d_in[1];
    const float* weights = (const float*)d_in[2];
    const int*   indices = (const int*)d_in[3];
    const float* gate    = (const float*)d_in[4];
    const float* up      = (const float*)d_in[5];
    const float* down    = (const float*)d_in[6];
    float*       y       = (float*)d_out;

    char* ws = (char*)d_ws;
    int*            counts  = (int*)ws;
    int*            offsets = (int*)(ws + 32);
    int*            tok     = (int*)(ws + 256);
    float*          wslot   = (float*)(ws + 256 + MAXROWS * 4);
    unsigned short* xb      = (unsigned short*)(ws + 65536);
    unsigned short* hb      = (unsigned short*)(ws + 65536 + (size_t)T_TOK * DDIM * 2);

    hipMemsetAsync(d_out, 0, (size_t)out_size * sizeof(float), stream);
    route_kernel<<<1, 256, 0, stream>>>(indices, weights, mask, counts, offsets, tok, wslot);
    cvt_x_kernel<<<(T_TOK * DDIM / 8) / 256, 256, 0, stream>>>(x, xb);

    dim3 g1(IDIM / BN, 16, NEXP);   // up to 1024 rows/expert
    gemm1_kernel<<<g1, 256, 0, stream>>>(xb, gate, up, counts, offsets, tok, hb);
    dim3 g2(DDIM / BN, 16, NEXP);
    gemm2_kernel<<<g2, 256, 0, stream>>>(hb, down, counts, offsets, tok, wslot, y);
}

// Round 13
// 134.137 us; speedup vs baseline: 2.5994x; 1.2238x over previous
//
#include <hip/hip_runtime.h>
#include <hip/hip_bf16.h>

#define T_TOK 2048
#define DDIM  1024
#define IDIM  1024
#define NEXP  8
#define TOPK  2
#define MAXROWS (T_TOK * TOPK)

#define BM 128
#define BN 64
#define BK 64

typedef __attribute__((ext_vector_type(8))) short          s16x8;
typedef __attribute__((ext_vector_type(8))) unsigned short u16x8;
typedef __attribute__((ext_vector_type(4))) float          f32x4;

__device__ __forceinline__ unsigned short f2bf(float f) {
    return __builtin_bit_cast(unsigned short, __float2bfloat16(f));
}

__device__ __forceinline__ u16x8 pack8(const float4& a, const float4& b) {
    u16x8 v;
    v[0] = f2bf(a.x); v[1] = f2bf(a.y); v[2] = f2bf(a.z); v[3] = f2bf(a.w);
    v[4] = f2bf(b.x); v[5] = f2bf(b.y); v[6] = f2bf(b.z); v[7] = f2bf(b.w);
    return v;
}

__device__ __forceinline__ s16x8 cvt8(const float4& a, const float4& b) {
    return __builtin_bit_cast(s16x8, pack8(a, b));
}

__device__ __forceinline__ void gll16(const void* g, void* l) {
    __builtin_amdgcn_global_load_lds(
        (const __attribute__((address_space(1))) void*)g,
        (__attribute__((address_space(3))) void*)l, 16, 0, 0);
}

// ---------------- routing ----------------
__global__ void route_kernel(const int* __restrict__ indices,
                             const float* __restrict__ weights,
                             const void* __restrict__ mask,
                             int* __restrict__ counts, int* __restrict__ offsets,
                             int* __restrict__ tok, float* __restrict__ wslot) {
    __shared__ int cnt[NEXP], offs[NEXP], cur[NEXP];
    __shared__ int is_u8;
    const int tid = threadIdx.x;
    const unsigned char* m8  = (const unsigned char*)mask;
    const int*           m32 = (const int*)mask;
    if (tid < NEXP) cnt[tid] = 0;
    if (tid == 0) is_u8 = 0;
    __syncthreads();
    int found = 0;
    for (int i = tid; i < T_TOK; i += blockDim.x)
        if ((i & 3) != 0 && m8[i] != 0) found = 1;
    if (found) atomicOr(&is_u8, 1);
    __syncthreads();
    const int u8mode = is_u8;
    for (int idx = tid; idx < MAXROWS; idx += blockDim.x) {
        int t = idx >> 1;
        int active = u8mode ? (m8[t] != 0) : (m32[t] != 0);
        if (active) atomicAdd(&cnt[indices[idx]], 1);
    }
    __syncthreads();
    if (tid == 0) {
        int run = 0;
        for (int e = 0; e < NEXP; ++e) { offs[e] = run; run += cnt[e]; }
    }
    __syncthreads();
    if (tid < NEXP) { counts[tid] = cnt[tid]; offsets[tid] = offs[tid]; cur[tid] = offs[tid]; }
    __syncthreads();
    for (int idx = tid; idx < MAXROWS; idx += blockDim.x) {
        int t = idx >> 1;
        int active = u8mode ? (m8[t] != 0) : (m32[t] != 0);
        if (active) {
            int e = indices[idx];
            int p = atomicAdd(&cur[e], 1);
            tok[p]   = t;
            wslot[p] = weights[idx];
        }
    }
}

// ---------------- x: f32 -> bf16 once ----------------
__global__ __launch_bounds__(256) void cvt_x_kernel(const float* __restrict__ x,
                                                    unsigned short* __restrict__ xb) {
    int i = (blockIdx.x * 256 + threadIdx.x) * 8;
    float4 a = *reinterpret_cast<const float4*>(x + i);
    float4 b = *reinterpret_cast<const float4*>(x + i + 4);
    *reinterpret_cast<u16x8*>(xb + i) = pack8(a, b);
}

// LDS layouts: 128-B rows, XOR swizzle slot ^= row&7 (R6-verified math).
// A (bf16): per K-half, [64 LDS rows][64 shorts]; row r holds tokens {2r,2r+1},
//   logical slot il = 2*kslot + (tok&1), stored at il^(r&7).
// B (f32): per K-half, [64 rows][32 floats]; logical slot il = k/4, at il^(row&7).

// ---------------- GEMM1: 128x64 tile, BK=64, single-buf 2-barrier (m97 structure) ----------------
__global__ __launch_bounds__(256, 2) void gemm1_kernel(
    const unsigned short* __restrict__ xb,
    const float* __restrict__ gate, const float* __restrict__ up,
    const int* __restrict__ counts, const int* __restrict__ offsets,
    const int* __restrict__ tok, unsigned short* __restrict__ hb) {
    const int e     = blockIdx.z;
    const int n_e   = counts[e];
    const int tileM = blockIdx.y;
    if (tileM * BM >= n_e) return;
    const int off = offsets[e];
    const int n0  = blockIdx.x * BN;

    __shared__ unsigned short lA[2][64 * 64];  // 2 x 8 KB
    __shared__ float          lG[2][64 * 32];  // 2 x 8 KB
    __shared__ float          lU[2][64 * 32];  // 2 x 8 KB  -> 48 KB

    const int tid  = threadIdx.x;
    const int lane = tid & 63;
    const int wid  = tid >> 6;
    const int fr   = lane & 15;
    const int s8   = lane >> 4;

    // staging source pointers (2 chunks of 8 LDS rows per wave per half)
    const unsigned short* aP[2];
    const float* gP[2];
    const float* uP[2];
#pragma unroll
    for (int g = 0; g < 2; ++g) {
        int rA = wid * 16 + 8 * g + (lane >> 3);
        int il = (lane & 7) ^ (rA & 7);
        int trA = 2 * rA + (il & 1);
        int rowIdxA = tileM * BM + trA;
        int tIdx = (rowIdxA < n_e) ? tok[off + rowIdxA] : tok[off];
        aP[g] = xb + (size_t)tIdx * DDIM + (il >> 1) * 8;
        gP[g] = gate + ((size_t)e * IDIM + n0 + rA) * DDIM + il * 4;
        uP[g] = up   + ((size_t)e * IDIM + n0 + rA) * DDIM + il * 4;
    }

    f32x4 accg[2][4] = {};
    f32x4 accu[2][4] = {};

    auto STAGE = [&](int t) {
        const int k0 = t * BK;
#pragma unroll
        for (int g = 0; g < 2; ++g) {
            const int rb = (wid * 16 + 8 * g);
            gll16(aP[g] + k0,      &lA[0][rb * 64]);
            gll16(aP[g] + k0 + 32, &lA[1][rb * 64]);
            gll16(gP[g] + k0,      &lG[0][rb * 32]);
            gll16(gP[g] + k0 + 32, &lG[1][rb * 32]);
            gll16(uP[g] + k0,      &lU[0][rb * 32]);
            gll16(uP[g] + k0 + 32, &lU[1][rb * 32]);
        }
    };

    auto COMPUTE = [&]() {
#pragma unroll
        for (int h = 0; h < 2; ++h) {
            s16x8 a[2];
#pragma unroll
            for (int m = 0; m < 2; ++m) {
                int trow = wid * 32 + m * 16 + fr;
                int r = trow >> 1, p = trow & 1;
                int is_ = (2 * s8 + p) ^ (r & 7);
                a[m] = *reinterpret_cast<const s16x8*>(&lA[h][r * 64 + is_ * 8]);
            }
            s16x8 bg[4], bu[4];
#pragma unroll
            for (int nf = 0; nf < 4; ++nf) {
                int n = nf * 16 + fr;
                int xr = n & 7;
                float4 g0 = *reinterpret_cast<const float4*>(&lG[h][n * 32 + ((2 * s8) ^ xr) * 4]);
                float4 g1 = *reinterpret_cast<const float4*>(&lG[h][n * 32 + ((2 * s8 + 1) ^ xr) * 4]);
                float4 u0 = *reinterpret_cast<const float4*>(&lU[h][n * 32 + ((2 * s8) ^ xr) * 4]);
                float4 u1 = *reinterpret_cast<const float4*>(&lU[h][n * 32 + ((2 * s8 + 1) ^ xr) * 4]);
                bg[nf] = cvt8(g0, g1);
                bu[nf] = cvt8(u0, u1);
            }
#pragma unroll
            for (int m = 0; m < 2; ++m)
#pragma unroll
                for (int nf = 0; nf < 4; ++nf) {
                    accg[m][nf] = __builtin_amdgcn_mfma_f32_16x16x32_bf16(a[m], bg[nf], accg[m][nf], 0, 0, 0);
                    accu[m][nf] = __builtin_amdgcn_mfma_f32_16x16x32_bf16(a[m], bu[nf], accu[m][nf], 0, 0, 0);
                }
        }
    };

    const int NT = DDIM / BK;  // 16
    for (int t = 0; t < NT; ++t) {
        STAGE(t);
        __syncthreads();   // drains staging; tile visible
        COMPUTE();
        __syncthreads();   // reads done before next STAGE overwrites
    }

    const int rbase = tileM * BM;
#pragma unroll
    for (int m = 0; m < 2; ++m)
#pragma unroll
        for (int nf = 0; nf < 4; ++nf)
#pragma unroll
            for (int j = 0; j < 4; ++j) {
                int rl = wid * 32 + m * 16 + s8 * 4 + j;
                if (rbase + rl < n_e) {
                    int col = n0 + nf * 16 + fr;
                    float g = accg[m][nf][j];
                    float u = accu[m][nf][j];
                    float h = (g / (1.0f + __expf(-g))) * u;
                    hb[(size_t)(off + rbase + rl) * IDIM + col] = f2bf(h);
                }
            }
}

// ---------------- GEMM2: 128x64 tile, BK=64, single-buf 2-barrier, weighted scatter ----------------
__global__ __launch_bounds__(256, 2) void gemm2_kernel(
    const unsigned short* __restrict__ hb, const float* __restrict__ down,
    const int* __restrict__ counts, const int* __restrict__ offsets,
    const int* __restrict__ tok, const float* __restrict__ wslot,
    float* __restrict__ y) {
    const int e     = blockIdx.z;
    const int n_e   = counts[e];
    const int tileM = blockIdx.y;
    if (tileM * BM >= n_e) return;
    const int off = offsets[e];
    const int n0  = blockIdx.x * BN;

    __shared__ unsigned short lA[2][64 * 64];  // 16 KB
    __shared__ float          lB[2][64 * 32];  // 16 KB -> 32 KB

    const int tid  = threadIdx.x;
    const int lane = tid & 63;
    const int wid  = tid >> 6;
    const int fr   = lane & 15;
    const int s8   = lane >> 4;

    const unsigned short* aP[2];
    const float* bP[2];
#pragma unroll
    for (int g = 0; g < 2; ++g) {
        int rA = wid * 16 + 8 * g + (lane >> 3);
        int il = (lane & 7) ^ (rA & 7);
        int trA = 2 * rA + (il & 1);
        int rowIdxA = tileM * BM + trA;
        int hrow = (rowIdxA < n_e) ? (off + rowIdxA) : off;
        aP[g] = hb + (size_t)hrow * IDIM + (il >> 1) * 8;
        bP[g] = down + ((size_t)e * DDIM + n0 + rA) * IDIM + il * 4;
    }

    f32x4 acc[2][4] = {};

    auto STAGE = [&](int t) {
        const int k0 = t * BK;
#pragma unroll
        for (int g = 0; g < 2; ++g) {
            const int rb = (wid * 16 + 8 * g);
            gll16(aP[g] + k0,      &lA[0][rb * 64]);
            gll16(aP[g] + k0 + 32, &lA[1][rb * 64]);
            gll16(bP[g] + k0,      &lB[0][rb * 32]);
            gll16(bP[g] + k0 + 32, &lB[1][rb * 32]);
        }
    };

    auto COMPUTE = [&]() {
#pragma unroll
        for (int h = 0; h < 2; ++h) {
            s16x8 a[2];
#pragma unroll
            for (int m = 0; m < 2; ++m) {
                int trow = wid * 32 + m * 16 + fr;
                int r = trow >> 1, p = trow & 1;
                int is_ = (2 * s8 + p) ^ (r & 7);
                a[m] = *reinterpret_cast<const s16x8*>(&lA[h][r * 64 + is_ * 8]);
            }
            s16x8 bf[4];
#pragma unroll
            for (int nf = 0; nf < 4; ++nf) {
                int n = nf * 16 + fr;
                int xr = n & 7;
                float4 b0 = *reinterpret_cast<const float4*>(&lB[h][n * 32 + ((2 * s8) ^ xr) * 4]);
                float4 b1 = *reinterpret_cast<const float4*>(&lB[h][n * 32 + ((2 * s8 + 1) ^ xr) * 4]);
                bf[nf] = cvt8(b0, b1);
            }
#pragma unroll
            for (int m = 0; m < 2; ++m)
#pragma unroll
                for (int nf = 0; nf < 4; ++nf)
                    acc[m][nf] = __builtin_amdgcn_mfma_f32_16x16x32_bf16(a[m], bf[nf], acc[m][nf], 0, 0, 0);
        }
    };

    const int NT = IDIM / BK;  // 16
    for (int t = 0; t < NT; ++t) {
        STAGE(t);
        __syncthreads();
        COMPUTE();
        __syncthreads();
    }

    const int rbase = tileM * BM;
#pragma unroll
    for (int m = 0; m < 2; ++m)
#pragma unroll
        for (int nf = 0; nf < 4; ++nf)
#pragma unroll
            for (int j = 0; j < 4; ++j) {
                int rl = wid * 32 + m * 16 + s8 * 4 + j;
                if (rbase + rl < n_e) {
                    int col = n0 + nf * 16 + fr;
                    int row = off + rbase + rl;
                    float v = acc[m][nf][j] * wslot[row];
                    atomicAdd(&y[(size_t)tok[row] * DDIM + col], v);
                }
            }
}

extern "C" void kernel_launch(void* const* d_in, const int* in_sizes, int n_in,
                              void* d_out, int out_size, void* d_ws, size_t ws_size,
                              hipStream_t stream) {
    const float* x       = (const float*)d_in[0];
    const void*  mask    = d_in[1];
    const float* weights = (const float*)d_in[2];
    const int*   indices = (const int*)d_in[3];
    const float* gate    = (const float*)d_in[4];
    const float* up      = (const float*)d_in[5];
    const float* down    = (const float*)d_in[6];
    float*       y       = (float*)d_out;

    char* ws = (char*)d_ws;
    int*            counts  = (int*)ws;
    int*            offsets = (int*)(ws + 32);
    int*            tok     = (int*)(ws + 256);
    float*          wslot   = (float*)(ws + 256 + MAXROWS * 4);
    unsigned short* xb      = (unsigned short*)(ws + 65536);
    unsigned short* hb      = (unsigned short*)(ws + 65536 + (size_t)T_TOK * DDIM * 2);

    hipMemsetAsync(d_out, 0, (size_t)out_size * sizeof(float), stream);
    route_kernel<<<1, 256, 0, stream>>>(indices, weights, mask, counts, offsets, tok, wslot);
    cvt_x_kernel<<<(T_TOK * DDIM / 8) / 256, 256, 0, stream>>>(x, xb);

    dim3 g1(IDIM / BN, 8, NEXP);   // up to 1024 rows/expert; ~4 active m-tiles
    gemm1_kernel<<<g1, 256, 0, stream>>>(xb, gate, up, counts, offsets, tok, hb);
    dim3 g2(DDIM / BN, 8, NEXP);
    gemm2_kernel<<<g2, 256, 0, stream>>>(hb, down, counts, offsets, tok, wslot, y);
}